// Round 9
// baseline (177.339 us; speedup 1.0000x reference)
//
#include <hip/hip_runtime.h>
#include <hip/hip_bf16.h>
#include <stdint.h>

typedef unsigned long long u64;

#define AN 15
#define HH 200
#define WW 320
#define HWSZ (HH*WW)          // 64000
#define PER (AN*HWSZ)         // 960000 anchors per image
#define NB 8
#define K_PRE 2000
#define K_POST 1000
#define SORTN 4096            // candidate slot array per image
#define SORT2 2048            // refined sort size
#define HBINS 4096
#define HBLK 64               // hist blocks per image
#define CBLK 16               // compact blocks per image
#define SLICE (SORTN/CBLK)    // 256 candidate slots per compact block
#define NMS_TH 0.7f
#define BBOX_CLIP_F 4.135166556742356f   // log(1000/16)

// padded LDS index for the sort: lane stride 72B -> <=4-way bank conflicts
#define PHI(x) ((x) + ((x) >> 3))

__device__ __forceinline__ unsigned keyOfU(unsigned u) {
    return (u & 0x80000000u) ? ~u : (u | 0x80000000u);
}
__device__ __forceinline__ float valOf(unsigned k) {
    unsigned u = (k & 0x80000000u) ? (k ^ 0x80000000u) : ~k;
    return __uint_as_float(u);
}

// ---------- zero-init gh + rh (256 KB) --------------------------------------
__global__ __launch_bounds__(256)
void z_init(uint4* __restrict__ z4) {
    z4[blockIdx.x * 256 + threadIdx.x] = make_uint4(0, 0, 0, 0);
}

// ---------- pass 1: dual private 12-bit hist -> global atomic flush ---------
__global__ __launch_bounds__(256)
void k_hist(const uint4* __restrict__ cls4, unsigned* __restrict__ gh) {
    int n = blockIdx.y;
    __shared__ unsigned lh[2][HBINS];          // 32 KB, even/odd thread copies
    for (int b = threadIdx.x; b < HBINS; b += 256) { lh[0][b] = 0; lh[1][b] = 0; }
    __syncthreads();
    unsigned* myh = lh[threadIdx.x & 1];
    const uint4* p = cls4 + (size_t)n * (PER / 4);
    int stride = gridDim.x * 256;
    int i = blockIdx.x * 256 + threadIdx.x;
    for (; i + stride < PER / 4; i += 2 * stride) {
        uint4 a = p[i];
        uint4 b = p[i + stride];
        atomicAdd(&myh[keyOfU(a.x) >> 20], 1u);
        atomicAdd(&myh[keyOfU(a.y) >> 20], 1u);
        atomicAdd(&myh[keyOfU(a.z) >> 20], 1u);
        atomicAdd(&myh[keyOfU(a.w) >> 20], 1u);
        atomicAdd(&myh[keyOfU(b.x) >> 20], 1u);
        atomicAdd(&myh[keyOfU(b.y) >> 20], 1u);
        atomicAdd(&myh[keyOfU(b.z) >> 20], 1u);
        atomicAdd(&myh[keyOfU(b.w) >> 20], 1u);
    }
    if (i < PER / 4) {
        uint4 a = p[i];
        atomicAdd(&myh[keyOfU(a.x) >> 20], 1u);
        atomicAdd(&myh[keyOfU(a.y) >> 20], 1u);
        atomicAdd(&myh[keyOfU(a.z) >> 20], 1u);
        atomicAdd(&myh[keyOfU(a.w) >> 20], 1u);
    }
    __syncthreads();
    unsigned* dst = gh + (size_t)n * HBINS;
    for (int b = threadIdx.x; b < HBINS; b += 256) {
        unsigned v = lh[0][b] + lh[1][b];
        if (v) atomicAdd(&dst[b], v);      // fire-and-forget
    }
}

// ---------- suffix-scan of per-image hist -> 12-bit threshold + cntA --------
__global__ __launch_bounds__(1024)
void k_sel(const unsigned* __restrict__ gh, unsigned* __restrict__ selT12,
           unsigned* __restrict__ cntA) {
    int n = blockIdx.x, t = threadIdx.x;
    __shared__ unsigned L[1024];
    uint4 v = *(const uint4*)(gh + (size_t)n * HBINS + 4 * t);
    unsigned sf[5];
    sf[3] = v.w; sf[2] = v.z + sf[3]; sf[1] = v.y + sf[2]; sf[0] = v.x + sf[1];
    L[t] = sf[0];
    __syncthreads();
    for (int off = 1; off < 1024; off <<= 1) {
        unsigned x = L[t] + ((t + off < 1024) ? L[t + off] : 0u);
        __syncthreads(); L[t] = x; __syncthreads();
    }
    unsigned tail = (t < 1023) ? L[t + 1] : 0u;
    sf[0] += tail; sf[1] += tail; sf[2] += tail; sf[3] += tail; sf[4] = tail;
#pragma unroll
    for (int e = 0; e < 4; ++e)
        if (sf[e] >= K_PRE && sf[e + 1] < K_PRE) {
            selT12[n] = 4u * t + e;
            cntA[n] = sf[e + 1];           // count strictly above bin T12
        }
}

// ---------- compact into slices + refine hist of bin T12 (bits [19:8]) ------
__global__ __launch_bounds__(256)
void k_compact(const uint4* __restrict__ cls4, const unsigned* __restrict__ selT12,
               u64* __restrict__ cand, unsigned* __restrict__ rh) {
    int n = blockIdx.y;
    unsigned t12 = selT12[n];
    __shared__ unsigned cnt;
    __shared__ unsigned rl[HBINS];             // 16 KB refine hist
    if (threadIdx.x == 0) cnt = 0;
    for (int b = threadIdx.x; b < HBINS; b += 256) rl[b] = 0;
    __syncthreads();
    u64* slice = cand + (size_t)n * SORTN + (size_t)blockIdx.x * SLICE;
    const uint4* p = cls4 + (size_t)n * (PER / 4);
    int stride = gridDim.x * 256;

#define PROC(vv, ii) {                                                        \
        unsigned kk[4] = {keyOfU((vv).x), keyOfU((vv).y), keyOfU((vv).z),     \
                          keyOfU((vv).w)};                                    \
        int i0 = (ii) * 4;                                                    \
        int a = i0 / HWSZ;                                                    \
        int r0 = i0 - a * HWSZ;                                               \
        _Pragma("unroll")                                                     \
        for (int c = 0; c < 4; ++c) {                                         \
            if ((kk[c] >> 20) >= t12) {                                       \
                if ((kk[c] >> 20) == t12)                                     \
                    atomicAdd(&rl[(kk[c] >> 8) & 4095u], 1u);                 \
                unsigned pos = atomicAdd(&cnt, 1u);                           \
                if (pos < SLICE) {                                            \
                    unsigned idx = (unsigned)((r0 + c) * AN + a);             \
                    slice[pos] = ((u64)kk[c] << 32) | (u64)(~idx);            \
                }                                                             \
            }                                                                 \
        }                                                                     \
    }

    int i = blockIdx.x * 256 + threadIdx.x;
    for (; i + 3 * stride < PER / 4; i += 4 * stride) {
        uint4 v0 = p[i];
        uint4 v1 = p[i + stride];
        uint4 v2 = p[i + 2 * stride];
        uint4 v3 = p[i + 3 * stride];
        PROC(v0, i) PROC(v1, i + stride) PROC(v2, i + 2 * stride) PROC(v3, i + 3 * stride)
    }
    for (; i < PER / 4; i += stride) { uint4 v0 = p[i]; PROC(v0, i) }
#undef PROC

    __syncthreads();
    unsigned c0 = cnt; if (c0 > SLICE) c0 = SLICE;
    for (unsigned t = c0 + threadIdx.x; t < SLICE; t += 256) slice[t] = 0ull;
    unsigned* dst = rh + (size_t)n * HBINS;
    for (int b = threadIdx.x; b < HBINS; b += 256) {
        unsigned v = rl[b];
        if (v) atomicAdd(&dst[b], v);
    }
}

// ---------- refine suffix-scan -> 24-bit threshold ---------------------------
__global__ __launch_bounds__(1024)
void k_sel2(const unsigned* __restrict__ rh, const unsigned* __restrict__ selT12,
            const unsigned* __restrict__ cntA, unsigned* __restrict__ selT24) {
    int n = blockIdx.x, t = threadIdx.x;
    __shared__ unsigned L[1024];
    uint4 v = *(const uint4*)(rh + (size_t)n * HBINS + 4 * t);
    unsigned sf[5];
    sf[3] = v.w; sf[2] = v.z + sf[3]; sf[1] = v.y + sf[2]; sf[0] = v.x + sf[1];
    L[t] = sf[0];
    __syncthreads();
    for (int off = 1; off < 1024; off <<= 1) {
        unsigned x = L[t] + ((t + off < 1024) ? L[t + off] : 0u);
        __syncthreads(); L[t] = x; __syncthreads();
    }
    unsigned tail = (t < 1023) ? L[t + 1] : 0u;
    sf[0] += tail; sf[1] += tail; sf[2] += tail; sf[3] += tail; sf[4] = tail;
    unsigned need = K_PRE - cntA[n];       // >= 1
#pragma unroll
    for (int e = 0; e < 4; ++e)
        if (sf[e] >= need && sf[e + 1] < need)
            selT24[n] = (selT12[n] << 12) | (4u * t + e);
}

// ---------- filter to <=2048 + register-hybrid bitonic sort ------------------
__global__ __launch_bounds__(256)
void k_sort(u64* __restrict__ cand, const unsigned* __restrict__ selT24) {
    int n = blockIdx.x;
    int tid = threadIdx.x;
    __shared__ u64 sb[PHI(SORT2 - 1) + 1];   // 2303 u64 = 18.4 KB
    __shared__ unsigned cnt;
    if (tid == 0) cnt = 0;
    __syncthreads();
    unsigned T24 = selT24[n];
    u64* src = cand + (size_t)n * SORTN;

    // filter 4096 slots -> candidates with key24 >= T24 (count in [2000,~2006])
    for (int s = 0; s < SORTN / 256; ++s) {
        u64 e = src[tid + s * 256];
        if ((unsigned)(e >> 40) >= T24) {
            unsigned pos = atomicAdd(&cnt, 1u);
            if (pos < SORT2) sb[PHI((int)pos)] = e;
        }
    }
    __syncthreads();
    unsigned c0 = cnt; if (c0 > SORT2) c0 = SORT2;
    for (unsigned t = c0 + tid; t < SORT2; t += 256) sb[PHI((int)t)] = 0ull;
    __syncthreads();

    u64 r[8];
#define CE(a_, b_, d_) { bool sw_ = (d_) ? (r[a_] < r[b_]) : (r[a_] > r[b_]); \
                         if (sw_) { u64 t_ = r[a_]; r[a_] = r[b_]; r[b_] = t_; } }

    {   // k=2 and k=4 levels fully in registers on own 8 elements
#pragma unroll
        for (int e = 0; e < 8; ++e) r[e] = sb[9 * tid + e];
        CE(0, 1, true)  CE(2, 3, false) CE(4, 5, true)  CE(6, 7, false)
        CE(0, 2, true)  CE(1, 3, true)  CE(4, 6, false) CE(5, 7, false)
        CE(0, 1, true)  CE(2, 3, true)  CE(4, 5, false) CE(6, 7, false)
#pragma unroll
        for (int e = 0; e < 8; ++e) sb[9 * tid + e] = r[e];
        __syncthreads();
    }

    for (int k = 8; k <= SORT2; k <<= 1) {
        for (int j = k >> 1; j >= 8; j >>= 1) {
#pragma unroll
            for (int s = 0; s < 4; ++s) {
                int c = tid + s * 256;       // 1024 CEs per phase
                int i = ((c & ~(j - 1)) << 1) | (c & (j - 1));
                int p = i | j;
                bool dir = (i & k) == 0;
                u64 a = sb[PHI(i)], b = sb[PHI(p)];
                bool sw = dir ? (a < b) : (a > b);
                if (sw) { sb[PHI(i)] = b; sb[PHI(p)] = a; }
            }
            __syncthreads();
        }
        {   // register pass: j = 4, 2, 1 (dir uniform per thread for k>=8)
            bool d = ((8 * tid) & k) == 0;
#pragma unroll
            for (int e = 0; e < 8; ++e) r[e] = sb[9 * tid + e];
            CE(0, 4, d) CE(1, 5, d) CE(2, 6, d) CE(3, 7, d)
            CE(0, 2, d) CE(1, 3, d) CE(4, 6, d) CE(5, 7, d)
            CE(0, 1, d) CE(2, 3, d) CE(4, 5, d) CE(6, 7, d)
#pragma unroll
            for (int e = 0; e < 8; ++e) sb[9 * tid + e] = r[e];
            __syncthreads();
        }
    }
#undef CE

    // coalesced write-back of the sorted top-2048
    for (int t = tid; t < SORT2; t += 256)
        src[t] = sb[PHI(t)];
}

// ---------- decode top-2000 + stable valid-first partition (wide gathers) ---
__global__ __launch_bounds__(1024)
void k_decode(const float* __restrict__ reg, const float* __restrict__ anchors,
              const int* __restrict__ pih, const int* __restrict__ piw,
              const u64* __restrict__ cand,
              float* __restrict__ boxes_s, float* __restrict__ scores_s) {
    int n = blockIdx.x;
    int tid = threadIdx.x;
    float fh = (float)(*pih);
    float fw = (float)(*piw);

    float bx[2][4]; float sc[2]; int pred[2];
#pragma unroll
    for (int q = 0; q < 2; ++q) {
        int t = tid + 1024 * q;
        pred[q] = 0; sc[q] = -1.0f;
        bx[q][0] = bx[q][1] = bx[q][2] = bx[q][3] = 0.f;
        if (t < K_PRE) {
            u64 e = cand[(size_t)n * SORTN + t];
            unsigned key = (unsigned)(e >> 32);
            unsigned idx = ~((unsigned)e);
            float v = valOf(key);
            float s = 1.0f / (1.0f + expf(-v));
            int a = (int)(idx % AN);
            int rr = (int)(idx / AN);
            size_t base = ((size_t)(n * AN + a) * 4) * HWSZ + rr;
            float dx = reg[base];
            float dy = reg[base + HWSZ];
            float dw = reg[base + 2 * (size_t)HWSZ];
            float dh = reg[base + 3 * (size_t)HWSZ];
            float4 an4 = ((const float4*)anchors)[idx];
            float wa = an4.z - an4.x, ha = an4.w - an4.y;
            float cxa = an4.x + 0.5f * wa, cya = an4.y + 0.5f * ha;
            dw = fminf(dw, BBOX_CLIP_F); dh = fminf(dh, BBOX_CLIP_F);
            float cx = dx * wa + cxa, cy = dy * ha + cya;
            float w = wa * expf(dw), h = ha * expf(dh);
            float x1 = cx - 0.5f * w, y1 = cy - 0.5f * h;
            float x2 = cx + 0.5f * w, y2 = cy + 0.5f * h;
            x1 = fminf(fmaxf(x1, 0.f), fw);
            y1 = fminf(fmaxf(y1, 0.f), fh);
            x2 = fminf(fmaxf(x2, 0.f), fw);
            y2 = fminf(fmaxf(y2, 0.f), fh);
            bool valid = ((x2 - x1) >= 1.0f) && ((y2 - y1) >= 1.0f);
            bx[q][0] = x1; bx[q][1] = y1; bx[q][2] = x2; bx[q][3] = y2;
            sc[q] = s; pred[q] = valid ? 1 : 0;
        }
    }

    // stable valid-first partition via per-wave ballots (2048 entries)
    __shared__ u64 ww[32];
    __shared__ int wpfx[33];
    int lane = tid & 63, wid = tid >> 6;     // 16 waves
#pragma unroll
    for (int q = 0; q < 2; ++q) {
        u64 bal = __ballot(pred[q] != 0);
        if (lane == 0) ww[wid + 16 * q] = bal;
    }
    __syncthreads();
    if (tid == 0) {
        int s = 0;
#pragma unroll
        for (int w2 = 0; w2 < 32; ++w2) { wpfx[w2] = s; s += (int)__popcll(ww[w2]); }
        wpfx[32] = s;
    }
    __syncthreads();
    int V = wpfx[32];

#pragma unroll
    for (int q = 0; q < 2; ++q) {
        int t = tid + 1024 * q;
        if (t < K_PRE) {
            int wi = t >> 6;
            int before = wpfx[wi] + (int)__popcll(ww[wi] & ((1ull << (unsigned)lane) - 1ull));
            int pos = pred[q] ? before : (V + (t - before));
            float4 b4; b4.x = bx[q][0]; b4.y = bx[q][1]; b4.z = bx[q][2]; b4.w = bx[q][3];
            ((float4*)boxes_s)[(size_t)n * K_PRE + pos] = b4;
            scores_s[(size_t)n * K_PRE + pos] = pred[q] ? sc[q] : -1.0f;
        }
    }
}

// ---------- transposed IoU mask: maskT[n][rowblk][col] = incoming edges -----
__global__ __launch_bounds__(256)
void k_maskT(const float* __restrict__ boxes_s, u64* __restrict__ maskT) {
    int n = blockIdx.y, cb = blockIdx.x;
    int lane = threadIdx.x & 63, w = threadIdx.x >> 6;
    __shared__ float4 rowbuf[4][64];
    int c = cb * 64 + lane;
    bool cok = c < K_PRE;
    float4 c4;
    if (cok) c4 = ((const float4*)boxes_s)[(size_t)n * K_PRE + c];
    else { c4.x = c4.y = c4.z = c4.w = 0.f; }
    float areaC = (c4.z - c4.x) * (c4.w - c4.y);

    for (int rb = w; rb < 32; rb += 4) {
        u64 bits = 0;
        if (rb <= cb) {
            int r = rb * 64 + lane;
            float4 r4;
            if (r < K_PRE) r4 = ((const float4*)boxes_s)[(size_t)n * K_PRE + r];
            else { r4.x = r4.y = r4.z = r4.w = 0.f; }
            rowbuf[w][lane] = r4;
            if (cok) {
                int bmax = c - rb * 64; if (bmax > 64) bmax = 64;
                for (int b = 0; b < bmax; ++b) {
                    float4 q = rowbuf[w][b];
                    float ix = fminf(c4.z, q.z) - fmaxf(c4.x, q.x); ix = fmaxf(ix, 0.f);
                    float iy = fminf(c4.w, q.w) - fmaxf(c4.y, q.y); iy = fmaxf(iy, 0.f);
                    float inter = ix * iy;
                    float areaR = (q.z - q.x) * (q.w - q.y);
                    float iou = inter / (areaR + areaC - inter);
                    if (iou > NMS_TH) bits |= (1ull << b);
                }
            }
        }
        maskT[((size_t)n * 32 + rb) * 2048 + c] = bits;
    }
}

// ---------- greedy NMS: ballot-fixpoint per 64-block + output (tail zeroed) -
__global__ __launch_bounds__(64)
void k_scanT(const u64* __restrict__ maskT, const float* __restrict__ boxes_s,
             const float* __restrict__ scores_s, float* __restrict__ out) {
    int n = blockIdx.x;
    int lane = threadIdx.x;       // 64 threads, single wave
    __shared__ float ls[2048];
    __shared__ u64 keptw[32];
    for (int i = lane; i < 2048; i += 64)
        ls[i] = (i < K_PRE) ? scores_s[(size_t)n * K_PRE + i] : -1.0f;
    if (lane < 32) keptw[lane] = 0ull;
    __syncthreads();

    const u64* mb = maskT + (size_t)n * 32 * 2048;
    int kept_total = 0;

    u64 wv[32];
#pragma unroll
    for (int rb = 0; rb < 32; ++rb) wv[rb] = mb[(size_t)rb * 2048 + lane];

    for (int f = 0; f < 32; ++f) {
        int c = f * 64 + lane;

        u64 wn[32];
        if (f < 31) {
            int cn = c + 64;
#pragma unroll
            for (int rb = 0; rb < 32; ++rb) wn[rb] = mb[(size_t)rb * 2048 + cn];
        }

        u64 hit = 0;
#pragma unroll
        for (int rb = 0; rb < 32; ++rb) hit |= (wv[rb] & keptw[rb]);
        bool ext = hit != 0ull;
        u64 diag = wv[f];

        bool v = (ls[c] >= 0.0f) && !ext;
        u64 kept = __ballot(v);
        while (true) {
            u64 nk = __ballot(v && ((diag & kept) == 0ull));
            if (nk == kept) break;
            kept = nk;
        }

        if ((kept >> lane) & 1ull) {
            int rank = kept_total + (int)__popcll(kept & ((1ull << lane) - 1ull));
            if (rank < K_POST) {
                float4 b4 = ((const float4*)boxes_s)[(size_t)n * K_PRE + c];
                ((float4*)out)[(size_t)n * K_POST + rank] = b4;
                out[(size_t)NB * K_POST * 4 + (size_t)n * K_POST + rank] = ls[c];
            }
        }
        kept_total += (int)__popcll(kept);
        if (lane == 0) keptw[f] = kept;
        if (kept_total >= K_POST || f == 31) break;
#pragma unroll
        for (int rb = 0; rb < 32; ++rb) wv[rb] = wn[rb];
    }

    // zero output tail (every output byte written each replay)
    int start = (kept_total < K_POST) ? kept_total : K_POST;
    float4 z4; z4.x = z4.y = z4.z = z4.w = 0.f;
    for (int rk = start + lane; rk < K_POST; rk += 64) {
        ((float4*)out)[(size_t)n * K_POST + rk] = z4;
        out[(size_t)NB * K_POST * 4 + (size_t)n * K_POST + rk] = 0.f;
    }
}

extern "C" void kernel_launch(void* const* d_in, const int* in_sizes, int n_in,
                              void* d_out, int out_size, void* d_ws, size_t ws_size,
                              hipStream_t stream) {
    const float* cls     = (const float*)d_in[0];
    const float* regr    = (const float*)d_in[1];
    const float* anchors = (const float*)d_in[2];
    const int*   pih     = (const int*)d_in[3];
    const int*   piw     = (const int*)d_in[4];
    float* out = (float*)d_out;

    char* w = (char*)d_ws;
    // Non-overlapping layout (ws_size ~ 480 MB, plenty):
    u64*      maskT   = (u64*)(w + 0);                 // 8*32*2048*8 = 4,194,304
    unsigned* gh      = (unsigned*)(w + 4194304);      // 8*4096*4    =   131,072
    unsigned* rh      = (unsigned*)(w + 4325376);      // 8*4096*4    =   131,072
    unsigned* selT12  = (unsigned*)(w + 4456448);      // 32
    unsigned* cntA    = (unsigned*)(w + 4456480);      // 32
    unsigned* selT24  = (unsigned*)(w + 4456512);      // 32 (pad to 4456576)
    u64*      cand    = (u64*)(w + 4456576);           // 8*4096*8    =   262,144
    float*    boxes_s = (float*)(w + 4718720);         // 8*2000*16   =   256,000
    float*    scores_s= (float*)(w + 4974720);         // 8*2000*4    =    64,000
    // end 5,038,720 bytes

    z_init<<<64, 256, 0, stream>>>((uint4*)gh);        // zeroes gh + rh (256 KB)
    k_hist<<<dim3(HBLK, NB), 256, 0, stream>>>((const uint4*)cls, gh);
    k_sel<<<NB, 1024, 0, stream>>>(gh, selT12, cntA);
    k_compact<<<dim3(CBLK, NB), 256, 0, stream>>>((const uint4*)cls, selT12, cand, rh);
    k_sel2<<<NB, 1024, 0, stream>>>(rh, selT12, cntA, selT24);
    k_sort<<<NB, 256, 0, stream>>>(cand, selT24);
    k_decode<<<NB, 1024, 0, stream>>>(regr, anchors, pih, piw,
                                      cand, boxes_s, scores_s);
    k_maskT<<<dim3(32, NB), 256, 0, stream>>>(boxes_s, maskT);
    k_scanT<<<NB, 64, 0, stream>>>(maskT, boxes_s, scores_s, out);
    (void)in_sizes; (void)n_in; (void)ws_size;
}

// Round 10
// 134.359 us; speedup vs baseline: 1.3199x; 1.3199x over previous
//
#include <hip/hip_runtime.h>
#include <hip/hip_bf16.h>
#include <stdint.h>

typedef unsigned long long u64;

#define AN 15
#define HH 200
#define WW 320
#define HWSZ (HH*WW)          // 64000
#define PER (AN*HWSZ)         // 960000 anchors per image
#define NB 8
#define K_PRE 2000
#define K_POST 1000
#define SORTN 4096            // candidate slot array per image
#define SORT2 2048            // refined sort size
#define HBINS 4096
#define HBLK 64               // hist blocks per image
#define CBLK 16               // compact blocks per image
#define SLICE (SORTN/CBLK)    // 256 candidate slots per compact block
#define NMS_TH 0.7f
#define BBOX_CLIP_F 4.135166556742356f   // log(1000/16)

// padded LDS index for the sort: lane stride 72B -> <=4-way bank conflicts
#define PHI(x) ((x) + ((x) >> 3))

__device__ __forceinline__ unsigned keyOfU(unsigned u) {
    return (u & 0x80000000u) ? ~u : (u | 0x80000000u);
}
__device__ __forceinline__ float valOf(unsigned k) {
    unsigned u = (k & 0x80000000u) ? (k ^ 0x80000000u) : ~k;
    return __uint_as_float(u);
}

// ---------- zero-init gh + rh (256 KB) --------------------------------------
__global__ __launch_bounds__(256)
void z_init(uint4* __restrict__ z4) {
    z4[blockIdx.x * 256 + threadIdx.x] = make_uint4(0, 0, 0, 0);
}

// ---------- pass 1: dual private 12-bit hist -> global atomic flush ---------
__global__ __launch_bounds__(256)
void k_hist(const uint4* __restrict__ cls4, unsigned* __restrict__ gh) {
    int n = blockIdx.y;
    __shared__ unsigned lh[2][HBINS];          // 32 KB, even/odd thread copies
    for (int b = threadIdx.x; b < HBINS; b += 256) { lh[0][b] = 0; lh[1][b] = 0; }
    __syncthreads();
    unsigned* myh = lh[threadIdx.x & 1];
    const uint4* p = cls4 + (size_t)n * (PER / 4);
    int stride = gridDim.x * 256;
    int i = blockIdx.x * 256 + threadIdx.x;
    for (; i + stride < PER / 4; i += 2 * stride) {
        uint4 a = p[i];
        uint4 b = p[i + stride];
        atomicAdd(&myh[keyOfU(a.x) >> 20], 1u);
        atomicAdd(&myh[keyOfU(a.y) >> 20], 1u);
        atomicAdd(&myh[keyOfU(a.z) >> 20], 1u);
        atomicAdd(&myh[keyOfU(a.w) >> 20], 1u);
        atomicAdd(&myh[keyOfU(b.x) >> 20], 1u);
        atomicAdd(&myh[keyOfU(b.y) >> 20], 1u);
        atomicAdd(&myh[keyOfU(b.z) >> 20], 1u);
        atomicAdd(&myh[keyOfU(b.w) >> 20], 1u);
    }
    if (i < PER / 4) {
        uint4 a = p[i];
        atomicAdd(&myh[keyOfU(a.x) >> 20], 1u);
        atomicAdd(&myh[keyOfU(a.y) >> 20], 1u);
        atomicAdd(&myh[keyOfU(a.z) >> 20], 1u);
        atomicAdd(&myh[keyOfU(a.w) >> 20], 1u);
    }
    __syncthreads();
    unsigned* dst = gh + (size_t)n * HBINS;
    for (int b = threadIdx.x; b < HBINS; b += 256) {
        unsigned v = lh[0][b] + lh[1][b];
        if (v) atomicAdd(&dst[b], v);      // fire-and-forget
    }
}

// ---------- suffix-scan of per-image hist -> 12-bit threshold + cntA --------
__global__ __launch_bounds__(1024)
void k_sel(const unsigned* __restrict__ gh, unsigned* __restrict__ selT12,
           unsigned* __restrict__ cntA) {
    int n = blockIdx.x, t = threadIdx.x;
    __shared__ unsigned L[1024];
    uint4 v = *(const uint4*)(gh + (size_t)n * HBINS + 4 * t);
    unsigned sf[5];
    sf[3] = v.w; sf[2] = v.z + sf[3]; sf[1] = v.y + sf[2]; sf[0] = v.x + sf[1];
    L[t] = sf[0];
    __syncthreads();
    for (int off = 1; off < 1024; off <<= 1) {
        unsigned x = L[t] + ((t + off < 1024) ? L[t + off] : 0u);
        __syncthreads(); L[t] = x; __syncthreads();
    }
    unsigned tail = (t < 1023) ? L[t + 1] : 0u;
    sf[0] += tail; sf[1] += tail; sf[2] += tail; sf[3] += tail; sf[4] = tail;
#pragma unroll
    for (int e = 0; e < 4; ++e)
        if (sf[e] >= K_PRE && sf[e + 1] < K_PRE) {
            selT12[n] = 4u * t + e;
            cntA[n] = sf[e + 1];           // count strictly above bin T12
        }
}

// ---------- compact into slices + refine hist of bin T12 (bits [19:8]) ------
__global__ __launch_bounds__(512)
void k_compact(const uint4* __restrict__ cls4, const unsigned* __restrict__ selT12,
               u64* __restrict__ cand, unsigned* __restrict__ rh) {
    int n = blockIdx.y;
    unsigned t12 = selT12[n];
    __shared__ unsigned cnt;
    __shared__ unsigned rl[HBINS];             // 16 KB refine hist
    if (threadIdx.x == 0) cnt = 0;
    for (int b = threadIdx.x; b < HBINS; b += 512) rl[b] = 0;
    __syncthreads();
    u64* slice = cand + (size_t)n * SORTN + (size_t)blockIdx.x * SLICE;
    const uint4* p = cls4 + (size_t)n * (PER / 4);
    int stride = gridDim.x * 512;

#define PROC(vv, ii) {                                                        \
        unsigned kk[4] = {keyOfU((vv).x), keyOfU((vv).y), keyOfU((vv).z),     \
                          keyOfU((vv).w)};                                    \
        int i0 = (ii) * 4;                                                    \
        int a = i0 / HWSZ;                                                    \
        int r0 = i0 - a * HWSZ;                                               \
        _Pragma("unroll")                                                     \
        for (int c = 0; c < 4; ++c) {                                         \
            if ((kk[c] >> 20) >= t12) {                                       \
                if ((kk[c] >> 20) == t12)                                     \
                    atomicAdd(&rl[(kk[c] >> 8) & 4095u], 1u);                 \
                unsigned pos = atomicAdd(&cnt, 1u);                           \
                if (pos < SLICE) {                                            \
                    unsigned idx = (unsigned)((r0 + c) * AN + a);             \
                    slice[pos] = ((u64)kk[c] << 32) | (u64)(~idx);            \
                }                                                             \
            }                                                                 \
        }                                                                     \
    }

    int i = blockIdx.x * 512 + threadIdx.x;
    for (; i + 3 * stride < PER / 4; i += 4 * stride) {
        uint4 v0 = p[i];
        uint4 v1 = p[i + stride];
        uint4 v2 = p[i + 2 * stride];
        uint4 v3 = p[i + 3 * stride];
        PROC(v0, i) PROC(v1, i + stride) PROC(v2, i + 2 * stride) PROC(v3, i + 3 * stride)
    }
    for (; i < PER / 4; i += stride) { uint4 v0 = p[i]; PROC(v0, i) }
#undef PROC

    __syncthreads();
    unsigned c0 = cnt; if (c0 > SLICE) c0 = SLICE;
    for (unsigned t = c0 + threadIdx.x; t < SLICE; t += 512) slice[t] = 0ull;
    unsigned* dst = rh + (size_t)n * HBINS;
    for (int b = threadIdx.x; b < HBINS; b += 512) {
        unsigned v = rl[b];
        if (v) atomicAdd(&dst[b], v);
    }
}

// ---------- refine suffix-scan -> 24-bit threshold ---------------------------
__global__ __launch_bounds__(1024)
void k_sel2(const unsigned* __restrict__ rh, const unsigned* __restrict__ selT12,
            const unsigned* __restrict__ cntA, unsigned* __restrict__ selT24) {
    int n = blockIdx.x, t = threadIdx.x;
    __shared__ unsigned L[1024];
    uint4 v = *(const uint4*)(rh + (size_t)n * HBINS + 4 * t);
    unsigned sf[5];
    sf[3] = v.w; sf[2] = v.z + sf[3]; sf[1] = v.y + sf[2]; sf[0] = v.x + sf[1];
    L[t] = sf[0];
    __syncthreads();
    for (int off = 1; off < 1024; off <<= 1) {
        unsigned x = L[t] + ((t + off < 1024) ? L[t + off] : 0u);
        __syncthreads(); L[t] = x; __syncthreads();
    }
    unsigned tail = (t < 1023) ? L[t + 1] : 0u;
    sf[0] += tail; sf[1] += tail; sf[2] += tail; sf[3] += tail; sf[4] = tail;
    unsigned need = K_PRE - cntA[n];       // >= 1
#pragma unroll
    for (int e = 0; e < 4; ++e)
        if (sf[e] >= need && sf[e + 1] < need)
            selT24[n] = (selT12[n] << 12) | (4u * t + e);
}

// ---------- filter to <=2048 + register-hybrid bitonic sort ------------------
__global__ __launch_bounds__(256)
void k_sort(u64* __restrict__ cand, const unsigned* __restrict__ selT24) {
    int n = blockIdx.x;
    int tid = threadIdx.x;
    __shared__ u64 sb[PHI(SORT2 - 1) + 1];   // 2303 u64 = 18.4 KB
    __shared__ unsigned cnt;
    if (tid == 0) cnt = 0;
    __syncthreads();
    unsigned T24 = selT24[n];
    u64* src = cand + (size_t)n * SORTN;

    // filter 4096 slots -> candidates with key24 >= T24 (count in [2000,~2006])
    for (int s = 0; s < SORTN / 256; ++s) {
        u64 e = src[tid + s * 256];
        if ((unsigned)(e >> 40) >= T24) {
            unsigned pos = atomicAdd(&cnt, 1u);
            if (pos < SORT2) sb[PHI((int)pos)] = e;
        }
    }
    __syncthreads();
    unsigned c0 = cnt; if (c0 > SORT2) c0 = SORT2;
    for (unsigned t = c0 + tid; t < SORT2; t += 256) sb[PHI((int)t)] = 0ull;
    __syncthreads();

    u64 r[8];
#define CE(a_, b_, d_) { bool sw_ = (d_) ? (r[a_] < r[b_]) : (r[a_] > r[b_]); \
                         if (sw_) { u64 t_ = r[a_]; r[a_] = r[b_]; r[b_] = t_; } }

    {   // k=2 and k=4 levels fully in registers on own 8 elements
#pragma unroll
        for (int e = 0; e < 8; ++e) r[e] = sb[9 * tid + e];
        CE(0, 1, true)  CE(2, 3, false) CE(4, 5, true)  CE(6, 7, false)
        CE(0, 2, true)  CE(1, 3, true)  CE(4, 6, false) CE(5, 7, false)
        CE(0, 1, true)  CE(2, 3, true)  CE(4, 5, false) CE(6, 7, false)
#pragma unroll
        for (int e = 0; e < 8; ++e) sb[9 * tid + e] = r[e];
        __syncthreads();
    }

    for (int k = 8; k <= SORT2; k <<= 1) {
        for (int j = k >> 1; j >= 8; j >>= 1) {
#pragma unroll
            for (int s = 0; s < 4; ++s) {
                int c = tid + s * 256;       // 1024 CEs per phase
                int i = ((c & ~(j - 1)) << 1) | (c & (j - 1));
                int p = i | j;
                bool dir = (i & k) == 0;
                u64 a = sb[PHI(i)], b = sb[PHI(p)];
                bool sw = dir ? (a < b) : (a > b);
                if (sw) { sb[PHI(i)] = b; sb[PHI(p)] = a; }
            }
            __syncthreads();
        }
        {   // register pass: j = 4, 2, 1 (dir uniform per thread for k>=8)
            bool d = ((8 * tid) & k) == 0;
#pragma unroll
            for (int e = 0; e < 8; ++e) r[e] = sb[9 * tid + e];
            CE(0, 4, d) CE(1, 5, d) CE(2, 6, d) CE(3, 7, d)
            CE(0, 2, d) CE(1, 3, d) CE(4, 6, d) CE(5, 7, d)
            CE(0, 1, d) CE(2, 3, d) CE(4, 5, d) CE(6, 7, d)
#pragma unroll
            for (int e = 0; e < 8; ++e) sb[9 * tid + e] = r[e];
            __syncthreads();
        }
    }
#undef CE

    // coalesced write-back of the sorted top-2048
    for (int t = tid; t < SORT2; t += 256)
        src[t] = sb[PHI(t)];
}

// ---------- decode top-2000 + stable valid-first partition (wide gathers) ---
__global__ __launch_bounds__(1024)
void k_decode(const float* __restrict__ reg, const float* __restrict__ anchors,
              const int* __restrict__ pih, const int* __restrict__ piw,
              const u64* __restrict__ cand,
              float* __restrict__ boxes_s, float* __restrict__ scores_s) {
    int n = blockIdx.x;
    int tid = threadIdx.x;
    float fh = (float)(*pih);
    float fw = (float)(*piw);

    float bx[2][4]; float sc[2]; int pred[2];
#pragma unroll
    for (int q = 0; q < 2; ++q) {
        int t = tid + 1024 * q;
        pred[q] = 0; sc[q] = -1.0f;
        bx[q][0] = bx[q][1] = bx[q][2] = bx[q][3] = 0.f;
        if (t < K_PRE) {
            u64 e = cand[(size_t)n * SORTN + t];
            unsigned key = (unsigned)(e >> 32);
            unsigned idx = ~((unsigned)e);
            float v = valOf(key);
            float s = 1.0f / (1.0f + expf(-v));
            int a = (int)(idx % AN);
            int rr = (int)(idx / AN);
            size_t base = ((size_t)(n * AN + a) * 4) * HWSZ + rr;
            float dx = reg[base];
            float dy = reg[base + HWSZ];
            float dw = reg[base + 2 * (size_t)HWSZ];
            float dh = reg[base + 3 * (size_t)HWSZ];
            float4 an4 = ((const float4*)anchors)[idx];
            float wa = an4.z - an4.x, ha = an4.w - an4.y;
            float cxa = an4.x + 0.5f * wa, cya = an4.y + 0.5f * ha;
            dw = fminf(dw, BBOX_CLIP_F); dh = fminf(dh, BBOX_CLIP_F);
            float cx = dx * wa + cxa, cy = dy * ha + cya;
            float w = wa * expf(dw), h = ha * expf(dh);
            float x1 = cx - 0.5f * w, y1 = cy - 0.5f * h;
            float x2 = cx + 0.5f * w, y2 = cy + 0.5f * h;
            x1 = fminf(fmaxf(x1, 0.f), fw);
            y1 = fminf(fmaxf(y1, 0.f), fh);
            x2 = fminf(fmaxf(x2, 0.f), fw);
            y2 = fminf(fmaxf(y2, 0.f), fh);
            bool valid = ((x2 - x1) >= 1.0f) && ((y2 - y1) >= 1.0f);
            bx[q][0] = x1; bx[q][1] = y1; bx[q][2] = x2; bx[q][3] = y2;
            sc[q] = s; pred[q] = valid ? 1 : 0;
        }
    }

    // stable valid-first partition via per-wave ballots (2048 entries)
    __shared__ u64 ww[32];
    __shared__ int wpfx[33];
    int lane = tid & 63, wid = tid >> 6;     // 16 waves
#pragma unroll
    for (int q = 0; q < 2; ++q) {
        u64 bal = __ballot(pred[q] != 0);
        if (lane == 0) ww[wid + 16 * q] = bal;
    }
    __syncthreads();
    if (tid == 0) {
        int s = 0;
#pragma unroll
        for (int w2 = 0; w2 < 32; ++w2) { wpfx[w2] = s; s += (int)__popcll(ww[w2]); }
        wpfx[32] = s;
    }
    __syncthreads();
    int V = wpfx[32];

#pragma unroll
    for (int q = 0; q < 2; ++q) {
        int t = tid + 1024 * q;
        if (t < K_PRE) {
            int wi = t >> 6;
            int before = wpfx[wi] + (int)__popcll(ww[wi] & ((1ull << (unsigned)lane) - 1ull));
            int pos = pred[q] ? before : (V + (t - before));
            float4 b4; b4.x = bx[q][0]; b4.y = bx[q][1]; b4.z = bx[q][2]; b4.w = bx[q][3];
            ((float4*)boxes_s)[(size_t)n * K_PRE + pos] = b4;
            scores_s[(size_t)n * K_PRE + pos] = pred[q] ? sc[q] : -1.0f;
        }
    }
}

// ---------- transposed IoU mask, triangular (rb,cb) tile per 64-thr block ---
// writes maskT[n][rb][c] for rb <= cb only; k_scanT never consults rb > f
// words with nonzero keptw, so unwritten words are harmless.
__global__ __launch_bounds__(64)
void k_maskT(const float* __restrict__ boxes_s, u64* __restrict__ maskT) {
    int n = blockIdx.y;
    int p = blockIdx.x;                      // 0..527 triangular pair index
    int lane = threadIdx.x;
    int cb = (int)((sqrtf(8.0f * (float)p + 1.0f) - 1.0f) * 0.5f);
    while ((cb + 1) * (cb + 2) / 2 <= p) ++cb;
    while (cb * (cb + 1) / 2 > p) --cb;
    int rb = p - cb * (cb + 1) / 2;          // 0 <= rb <= cb < 32

    __shared__ float rx1[64], ry1[64], rx2[64], ry2[64], rar[64];
    int c = cb * 64 + lane;
    bool cok = c < K_PRE;
    float4 c4; c4.x = c4.y = c4.z = c4.w = 0.f;
    if (cok) c4 = ((const float4*)boxes_s)[(size_t)n * K_PRE + c];
    float areaC = (c4.z - c4.x) * (c4.w - c4.y);

    int r = rb * 64 + lane;
    float4 r4; r4.x = r4.y = r4.z = r4.w = 0.f;
    if (r < K_PRE) r4 = ((const float4*)boxes_s)[(size_t)n * K_PRE + r];
    rx1[lane] = r4.x; ry1[lane] = r4.y; rx2[lane] = r4.z; ry2[lane] = r4.w;
    rar[lane] = (r4.z - r4.x) * (r4.w - r4.y);
    __syncthreads();

    u64 bits = 0;
    int bmax = 0;
    if (cok) { bmax = c - rb * 64; if (bmax > 64) bmax = 64; }
    for (int b = 0; b < bmax; ++b) {
        float ix = fminf(c4.z, rx2[b]) - fmaxf(c4.x, rx1[b]); ix = fmaxf(ix, 0.f);
        float iy = fminf(c4.w, ry2[b]) - fmaxf(c4.y, ry1[b]); iy = fmaxf(iy, 0.f);
        float inter = ix * iy;
        float iou = inter / (rar[b] + areaC - inter);
        if (iou > NMS_TH) bits |= (1ull << b);
    }
    maskT[((size_t)n * 32 + rb) * 2048 + c] = bits;
}

// ---------- greedy NMS: ballot-fixpoint per 64-block + output (tail zeroed) -
__global__ __launch_bounds__(64)
void k_scanT(const u64* __restrict__ maskT, const float* __restrict__ boxes_s,
             const float* __restrict__ scores_s, float* __restrict__ out) {
    int n = blockIdx.x;
    int lane = threadIdx.x;       // 64 threads, single wave
    __shared__ float ls[2048];
    __shared__ u64 keptw[32];
    for (int i = lane; i < 2048; i += 64)
        ls[i] = (i < K_PRE) ? scores_s[(size_t)n * K_PRE + i] : -1.0f;
    if (lane < 32) keptw[lane] = 0ull;
    __syncthreads();

    const u64* mb = maskT + (size_t)n * 32 * 2048;
    int kept_total = 0;

    u64 wv[32];
#pragma unroll
    for (int rb = 0; rb < 32; ++rb) wv[rb] = mb[(size_t)rb * 2048 + lane];

    for (int f = 0; f < 32; ++f) {
        int c = f * 64 + lane;

        u64 wn[32];
        if (f < 31) {
            int cn = c + 64;
#pragma unroll
            for (int rb = 0; rb < 32; ++rb) wn[rb] = mb[(size_t)rb * 2048 + cn];
        }

        // rb > f words may be unwritten garbage, but keptw[rb>=f] == 0
        u64 hit = 0;
#pragma unroll
        for (int rb = 0; rb < 32; ++rb) hit |= (wv[rb] & keptw[rb]);
        bool ext = hit != 0ull;
        u64 diag = wv[f];

        bool v = (ls[c] >= 0.0f) && !ext;
        u64 kept = __ballot(v);
        while (true) {
            u64 nk = __ballot(v && ((diag & kept) == 0ull));
            if (nk == kept) break;
            kept = nk;
        }

        if ((kept >> lane) & 1ull) {
            int rank = kept_total + (int)__popcll(kept & ((1ull << lane) - 1ull));
            if (rank < K_POST) {
                float4 b4 = ((const float4*)boxes_s)[(size_t)n * K_PRE + c];
                ((float4*)out)[(size_t)n * K_POST + rank] = b4;
                out[(size_t)NB * K_POST * 4 + (size_t)n * K_POST + rank] = ls[c];
            }
        }
        kept_total += (int)__popcll(kept);
        if (lane == 0) keptw[f] = kept;
        if (kept_total >= K_POST || f == 31) break;
#pragma unroll
        for (int rb = 0; rb < 32; ++rb) wv[rb] = wn[rb];
    }

    // zero output tail (every output byte written each replay)
    int start = (kept_total < K_POST) ? kept_total : K_POST;
    float4 z4; z4.x = z4.y = z4.z = z4.w = 0.f;
    for (int rk = start + lane; rk < K_POST; rk += 64) {
        ((float4*)out)[(size_t)n * K_POST + rk] = z4;
        out[(size_t)NB * K_POST * 4 + (size_t)n * K_POST + rk] = 0.f;
    }
}

extern "C" void kernel_launch(void* const* d_in, const int* in_sizes, int n_in,
                              void* d_out, int out_size, void* d_ws, size_t ws_size,
                              hipStream_t stream) {
    const float* cls     = (const float*)d_in[0];
    const float* regr    = (const float*)d_in[1];
    const float* anchors = (const float*)d_in[2];
    const int*   pih     = (const int*)d_in[3];
    const int*   piw     = (const int*)d_in[4];
    float* out = (float*)d_out;

    char* w = (char*)d_ws;
    u64*      maskT   = (u64*)(w + 0);                 // 8*32*2048*8 = 4,194,304
    unsigned* gh      = (unsigned*)(w + 4194304);      // 8*4096*4    =   131,072
    unsigned* rh      = (unsigned*)(w + 4325376);      // 8*4096*4    =   131,072
    unsigned* selT12  = (unsigned*)(w + 4456448);      // 32
    unsigned* cntA    = (unsigned*)(w + 4456480);      // 32
    unsigned* selT24  = (unsigned*)(w + 4456512);      // 32 (pad to 4456576)
    u64*      cand    = (u64*)(w + 4456576);           // 8*4096*8    =   262,144
    float*    boxes_s = (float*)(w + 4718720);         // 8*2000*16   =   256,000
    float*    scores_s= (float*)(w + 4974720);         // 8*2000*4    =    64,000
    // end 5,038,720 bytes

    z_init<<<64, 256, 0, stream>>>((uint4*)gh);        // zeroes gh + rh (256 KB)
    k_hist<<<dim3(HBLK, NB), 256, 0, stream>>>((const uint4*)cls, gh);
    k_sel<<<NB, 1024, 0, stream>>>(gh, selT12, cntA);
    k_compact<<<dim3(CBLK, NB), 512, 0, stream>>>((const uint4*)cls, selT12, cand, rh);
    k_sel2<<<NB, 1024, 0, stream>>>(rh, selT12, cntA, selT24);
    k_sort<<<NB, 256, 0, stream>>>(cand, selT24);
    k_decode<<<NB, 1024, 0, stream>>>(regr, anchors, pih, piw,
                                      cand, boxes_s, scores_s);
    k_maskT<<<dim3(528, NB), 64, 0, stream>>>(boxes_s, maskT);
    k_scanT<<<NB, 64, 0, stream>>>(maskT, boxes_s, scores_s, out);
    (void)in_sizes; (void)n_in; (void)ws_size;
}

// Round 11
// 127.369 us; speedup vs baseline: 1.3923x; 1.0549x over previous
//
#include <hip/hip_runtime.h>
#include <hip/hip_bf16.h>
#include <stdint.h>

typedef unsigned long long u64;

#define AN 15
#define HH 200
#define WW 320
#define HWSZ (HH*WW)          // 64000
#define PER (AN*HWSZ)         // 960000 anchors per image
#define NB 8
#define K_PRE 2000
#define K_POST 1000
#define SORTN 4096            // candidate slot array per image
#define HBINS 4096
#define HBLK 64               // hist blocks per image
#define CBLK 16               // compact blocks per image
#define SLICE (SORTN/CBLK)    // 256 candidate slots per compact block
#define NMS_TH 0.7f
#define BBOX_CLIP_F 4.135166556742356f   // log(1000/16)
#define FLOOR12 3072u         // key12 of value 2.0f; P(x>=2.0)~2.3% for N(0,1)
#define SENT 0xFFFFFFFFu

// padded LDS index for the sort: lane stride 72B -> <=4-way bank conflicts
#define PHI(x) ((x) + ((x) >> 3))

__device__ __forceinline__ unsigned keyOfU(unsigned u) {
    return (u & 0x80000000u) ? ~u : (u | 0x80000000u);
}
__device__ __forceinline__ float valOf(unsigned k) {
    unsigned u = (k & 0x80000000u) ? (k ^ 0x80000000u) : ~k;
    return __uint_as_float(u);
}

// ---------- zero-init gh (131 KB) + selT12 sentinels ------------------------
__global__ __launch_bounds__(256)
void z_init(uint4* __restrict__ gh4, unsigned* __restrict__ selT12) {
    gh4[blockIdx.x * 256 + threadIdx.x] = make_uint4(0, 0, 0, 0);
    if (blockIdx.x == 0 && threadIdx.x < NB) selT12[threadIdx.x] = SENT;
}

// ---------- pass 1: floored 12-bit hist (atomics only for ~2.3% of keys) ----
__global__ __launch_bounds__(256)
void k_histF(const uint4* __restrict__ cls4, unsigned* __restrict__ gh) {
    int n = blockIdx.y;
    __shared__ unsigned lh[HBINS];             // 16 KB
    for (int b = threadIdx.x; b < HBINS; b += 256) lh[b] = 0;
    __syncthreads();
    const uint4* p = cls4 + (size_t)n * (PER / 4);
    int stride = gridDim.x * 256;
    int i = blockIdx.x * 256 + threadIdx.x;
#define H4(vv) { unsigned k0 = keyOfU((vv).x) >> 20, k1 = keyOfU((vv).y) >> 20, \
                          k2 = keyOfU((vv).z) >> 20, k3 = keyOfU((vv).w) >> 20; \
        if (k0 >= FLOOR12) atomicAdd(&lh[k0], 1u);                              \
        if (k1 >= FLOOR12) atomicAdd(&lh[k1], 1u);                              \
        if (k2 >= FLOOR12) atomicAdd(&lh[k2], 1u);                              \
        if (k3 >= FLOOR12) atomicAdd(&lh[k3], 1u); }
    for (; i + stride < PER / 4; i += 2 * stride) {
        uint4 a = p[i];
        uint4 b = p[i + stride];
        H4(a) H4(b)
    }
    if (i < PER / 4) { uint4 a = p[i]; H4(a) }
#undef H4
    __syncthreads();
    unsigned* dst = gh + (size_t)n * HBINS;
    for (int b = threadIdx.x; b < HBINS; b += 256) {
        unsigned v = lh[b];
        if (v) atomicAdd(&dst[b], v);      // few nonzero bins, fire-and-forget
    }
}

// ---------- suffix-scan -> 12-bit threshold (writes only if crossing found) -
__global__ __launch_bounds__(1024)
void k_sel(const unsigned* __restrict__ gh, unsigned* __restrict__ selT12) {
    int n = blockIdx.x, t = threadIdx.x;
    __shared__ unsigned L[1024];
    uint4 v = *(const uint4*)(gh + (size_t)n * HBINS + 4 * t);
    unsigned sf[5];
    sf[3] = v.w; sf[2] = v.z + sf[3]; sf[1] = v.y + sf[2]; sf[0] = v.x + sf[1];
    L[t] = sf[0];
    __syncthreads();
    for (int off = 1; off < 1024; off <<= 1) {
        unsigned x = L[t] + ((t + off < 1024) ? L[t + off] : 0u);
        __syncthreads(); L[t] = x; __syncthreads();
    }
    unsigned tail = (t < 1023) ? L[t + 1] : 0u;
    sf[0] += tail; sf[1] += tail; sf[2] += tail; sf[3] += tail; sf[4] = tail;
#pragma unroll
    for (int e = 0; e < 4; ++e)
        if (sf[e] >= K_PRE && sf[e + 1] < K_PRE) selT12[n] = 4u * t + e;
}

// ---------- fallback: complete hist for keys < floor (early-exit if done) ---
__global__ __launch_bounds__(256)
void k_histR(const uint4* __restrict__ cls4, unsigned* __restrict__ gh,
             const unsigned* __restrict__ selT12) {
    int n = blockIdx.y;
    if (selT12[n] != SENT) return;             // normal case: ~free
    __shared__ unsigned lh[HBINS];
    for (int b = threadIdx.x; b < HBINS; b += 256) lh[b] = 0;
    __syncthreads();
    const uint4* p = cls4 + (size_t)n * (PER / 4);
    int stride = gridDim.x * 256;
#define H4(vv) { unsigned k0 = keyOfU((vv).x) >> 20, k1 = keyOfU((vv).y) >> 20, \
                          k2 = keyOfU((vv).z) >> 20, k3 = keyOfU((vv).w) >> 20; \
        if (k0 < FLOOR12) atomicAdd(&lh[k0], 1u);                               \
        if (k1 < FLOOR12) atomicAdd(&lh[k1], 1u);                               \
        if (k2 < FLOOR12) atomicAdd(&lh[k2], 1u);                               \
        if (k3 < FLOOR12) atomicAdd(&lh[k3], 1u); }
    for (int i = blockIdx.x * 256 + threadIdx.x; i < PER / 4; i += stride) {
        uint4 a = p[i]; H4(a)
    }
#undef H4
    __syncthreads();
    unsigned* dst = gh + (size_t)n * HBINS;
    for (int b = threadIdx.x; b < HBINS; b += 256) {
        unsigned v = lh[b];
        if (v) atomicAdd(&dst[b], v);
    }
}

__global__ __launch_bounds__(1024)
void k_selR(const unsigned* __restrict__ gh, unsigned* __restrict__ selT12) {
    int n = blockIdx.x, t = threadIdx.x;
    if (selT12[n] != SENT) return;
    __shared__ unsigned L[1024];
    uint4 v = *(const uint4*)(gh + (size_t)n * HBINS + 4 * t);
    unsigned sf[5];
    sf[3] = v.w; sf[2] = v.z + sf[3]; sf[1] = v.y + sf[2]; sf[0] = v.x + sf[1];
    L[t] = sf[0];
    __syncthreads();
    for (int off = 1; off < 1024; off <<= 1) {
        unsigned x = L[t] + ((t + off < 1024) ? L[t + off] : 0u);
        __syncthreads(); L[t] = x; __syncthreads();
    }
    unsigned tail = (t < 1023) ? L[t + 1] : 0u;
    sf[0] += tail; sf[1] += tail; sf[2] += tail; sf[3] += tail; sf[4] = tail;
#pragma unroll
    for (int e = 0; e < 4; ++e)
        if (sf[e] >= K_PRE && sf[e + 1] < K_PRE) selT12[n] = 4u * t + e;
    // if still no crossing (fewer than 2000 anchors total - impossible here),
    // selT12 stays SENT; compact would then select everything (capped), which
    // can only occur for degenerate inputs.
}

// ---------- compact into fixed per-block slices (no refine hist) ------------
__global__ __launch_bounds__(512)
void k_compact(const uint4* __restrict__ cls4, const unsigned* __restrict__ selT12,
               u64* __restrict__ cand) {
    int n = blockIdx.y;
    unsigned t12 = selT12[n];
    __shared__ unsigned cnt;
    if (threadIdx.x == 0) cnt = 0;
    __syncthreads();
    u64* slice = cand + (size_t)n * SORTN + (size_t)blockIdx.x * SLICE;
    const uint4* p = cls4 + (size_t)n * (PER / 4);
    int stride = gridDim.x * 512;

#define PROC(vv, ii) {                                                        \
        unsigned kk[4] = {keyOfU((vv).x), keyOfU((vv).y), keyOfU((vv).z),     \
                          keyOfU((vv).w)};                                    \
        int i0 = (ii) * 4;                                                    \
        int a = i0 / HWSZ;                                                    \
        int r0 = i0 - a * HWSZ;                                               \
        _Pragma("unroll")                                                     \
        for (int c = 0; c < 4; ++c) {                                         \
            if ((kk[c] >> 20) >= t12) {                                       \
                unsigned pos = atomicAdd(&cnt, 1u);                           \
                if (pos < SLICE) {                                            \
                    unsigned idx = (unsigned)((r0 + c) * AN + a);             \
                    slice[pos] = ((u64)kk[c] << 32) | (u64)(~idx);            \
                }                                                             \
            }                                                                 \
        }                                                                     \
    }

    int i = blockIdx.x * 512 + threadIdx.x;
    for (; i + 3 * stride < PER / 4; i += 4 * stride) {
        uint4 v0 = p[i];
        uint4 v1 = p[i + stride];
        uint4 v2 = p[i + 2 * stride];
        uint4 v3 = p[i + 3 * stride];
        PROC(v0, i) PROC(v1, i + stride) PROC(v2, i + 2 * stride) PROC(v3, i + 3 * stride)
    }
    for (; i < PER / 4; i += stride) { uint4 v0 = p[i]; PROC(v0, i) }
#undef PROC

    __syncthreads();
    unsigned c0 = cnt; if (c0 > SLICE) c0 = SLICE;
    for (unsigned t = c0 + threadIdx.x; t < SLICE; t += 512) slice[t] = 0ull;
}

// ---------- register-hybrid bitonic sort of 4096 (PHI-padded LDS) -----------
__global__ __launch_bounds__(512)
void k_sort(u64* __restrict__ cand) {
    int n = blockIdx.x;
    int tid = threadIdx.x;
    __shared__ u64 sb[PHI(SORTN - 1) + 1];   // 4607 u64 = 36.9 KB
    u64 r[8];

#define CE(a_, b_, d_) { bool sw_ = (d_) ? (r[a_] < r[b_]) : (r[a_] > r[b_]); \
                         if (sw_) { u64 t_ = r[a_]; r[a_] = r[b_]; r[b_] = t_; } }

    {   // load own 8 elements, run k=2 and k=4 levels fully in registers
        const u64* src = cand + (size_t)n * SORTN + 8 * tid;
#pragma unroll
        for (int e = 0; e < 8; ++e) r[e] = src[e];
        CE(0, 1, true)  CE(2, 3, false) CE(4, 5, true)  CE(6, 7, false)
        CE(0, 2, true)  CE(1, 3, true)  CE(4, 6, false) CE(5, 7, false)
        CE(0, 1, true)  CE(2, 3, true)  CE(4, 5, false) CE(6, 7, false)
#pragma unroll
        for (int e = 0; e < 8; ++e) sb[9 * tid + e] = r[e];   // PHI(8t+e)
        __syncthreads();
    }

    for (int k = 8; k <= SORTN; k <<= 1) {
        for (int j = k >> 1; j >= 8; j >>= 1) {
#pragma unroll
            for (int s = 0; s < 4; ++s) {
                int c = tid + s * 512;
                int i = ((c & ~(j - 1)) << 1) | (c & (j - 1));
                int p = i | j;
                bool dir = (i & k) == 0;
                u64 a = sb[PHI(i)], b = sb[PHI(p)];
                bool sw = dir ? (a < b) : (a > b);
                if (sw) { sb[PHI(i)] = b; sb[PHI(p)] = a; }
            }
            __syncthreads();
        }
        {   // register pass: j = 4, 2, 1 (dir uniform per thread for k>=8)
            bool d = ((8 * tid) & k) == 0;
#pragma unroll
            for (int e = 0; e < 8; ++e) r[e] = sb[9 * tid + e];
            CE(0, 4, d) CE(1, 5, d) CE(2, 6, d) CE(3, 7, d)
            CE(0, 2, d) CE(1, 3, d) CE(4, 6, d) CE(5, 7, d)
            CE(0, 1, d) CE(2, 3, d) CE(4, 5, d) CE(6, 7, d)
#pragma unroll
            for (int e = 0; e < 8; ++e) sb[9 * tid + e] = r[e];
            __syncthreads();
        }
    }
#undef CE

    // write back only the top-2048 (decode reads top-2000)
    for (int t = tid; t < 2048; t += 512)
        cand[(size_t)n * SORTN + t] = sb[PHI(t)];
}

// ---------- decode top-2000 + stable valid-first partition (wide gathers) ---
__global__ __launch_bounds__(1024)
void k_decode(const float* __restrict__ reg, const float* __restrict__ anchors,
              const int* __restrict__ pih, const int* __restrict__ piw,
              const u64* __restrict__ cand,
              float* __restrict__ boxes_s, float* __restrict__ scores_s) {
    int n = blockIdx.x;
    int tid = threadIdx.x;
    float fh = (float)(*pih);
    float fw = (float)(*piw);

    float bx[2][4]; float sc[2]; int pred[2];
#pragma unroll
    for (int q = 0; q < 2; ++q) {
        int t = tid + 1024 * q;
        pred[q] = 0; sc[q] = -1.0f;
        bx[q][0] = bx[q][1] = bx[q][2] = bx[q][3] = 0.f;
        if (t < K_PRE) {
            u64 e = cand[(size_t)n * SORTN + t];
            unsigned key = (unsigned)(e >> 32);
            unsigned idx = ~((unsigned)e);
            float v = valOf(key);
            float s = 1.0f / (1.0f + expf(-v));
            int a = (int)(idx % AN);
            int rr = (int)(idx / AN);
            size_t base = ((size_t)(n * AN + a) * 4) * HWSZ + rr;
            float dx = reg[base];
            float dy = reg[base + HWSZ];
            float dw = reg[base + 2 * (size_t)HWSZ];
            float dh = reg[base + 3 * (size_t)HWSZ];
            float4 an4 = ((const float4*)anchors)[idx];
            float wa = an4.z - an4.x, ha = an4.w - an4.y;
            float cxa = an4.x + 0.5f * wa, cya = an4.y + 0.5f * ha;
            dw = fminf(dw, BBOX_CLIP_F); dh = fminf(dh, BBOX_CLIP_F);
            float cx = dx * wa + cxa, cy = dy * ha + cya;
            float w = wa * expf(dw), h = ha * expf(dh);
            float x1 = cx - 0.5f * w, y1 = cy - 0.5f * h;
            float x2 = cx + 0.5f * w, y2 = cy + 0.5f * h;
            x1 = fminf(fmaxf(x1, 0.f), fw);
            y1 = fminf(fmaxf(y1, 0.f), fh);
            x2 = fminf(fmaxf(x2, 0.f), fw);
            y2 = fminf(fmaxf(y2, 0.f), fh);
            bool valid = ((x2 - x1) >= 1.0f) && ((y2 - y1) >= 1.0f);
            bx[q][0] = x1; bx[q][1] = y1; bx[q][2] = x2; bx[q][3] = y2;
            sc[q] = s; pred[q] = valid ? 1 : 0;
        }
    }

    // stable valid-first partition via per-wave ballots (2048 entries)
    __shared__ u64 ww[32];
    __shared__ int wpfx[33];
    int lane = tid & 63, wid = tid >> 6;     // 16 waves
#pragma unroll
    for (int q = 0; q < 2; ++q) {
        u64 bal = __ballot(pred[q] != 0);
        if (lane == 0) ww[wid + 16 * q] = bal;
    }
    __syncthreads();
    if (tid == 0) {
        int s = 0;
#pragma unroll
        for (int w2 = 0; w2 < 32; ++w2) { wpfx[w2] = s; s += (int)__popcll(ww[w2]); }
        wpfx[32] = s;
    }
    __syncthreads();
    int V = wpfx[32];

#pragma unroll
    for (int q = 0; q < 2; ++q) {
        int t = tid + 1024 * q;
        if (t < K_PRE) {
            int wi = t >> 6;
            int before = wpfx[wi] + (int)__popcll(ww[wi] & ((1ull << (unsigned)lane) - 1ull));
            int pos = pred[q] ? before : (V + (t - before));
            float4 b4; b4.x = bx[q][0]; b4.y = bx[q][1]; b4.z = bx[q][2]; b4.w = bx[q][3];
            ((float4*)boxes_s)[(size_t)n * K_PRE + pos] = b4;
            scores_s[(size_t)n * K_PRE + pos] = pred[q] ? sc[q] : -1.0f;
        }
    }
}

// ---------- transposed IoU mask, triangular (rb,cb) tile per 64-thr block ---
__global__ __launch_bounds__(64)
void k_maskT(const float* __restrict__ boxes_s, u64* __restrict__ maskT) {
    int n = blockIdx.y;
    int p = blockIdx.x;                      // 0..527 triangular pair index
    int lane = threadIdx.x;
    int cb = (int)((sqrtf(8.0f * (float)p + 1.0f) - 1.0f) * 0.5f);
    while ((cb + 1) * (cb + 2) / 2 <= p) ++cb;
    while (cb * (cb + 1) / 2 > p) --cb;
    int rb = p - cb * (cb + 1) / 2;          // 0 <= rb <= cb < 32

    __shared__ float rx1[64], ry1[64], rx2[64], ry2[64], rar[64];
    int c = cb * 64 + lane;
    bool cok = c < K_PRE;
    float4 c4; c4.x = c4.y = c4.z = c4.w = 0.f;
    if (cok) c4 = ((const float4*)boxes_s)[(size_t)n * K_PRE + c];
    float areaC = (c4.z - c4.x) * (c4.w - c4.y);

    int r = rb * 64 + lane;
    float4 r4; r4.x = r4.y = r4.z = r4.w = 0.f;
    if (r < K_PRE) r4 = ((const float4*)boxes_s)[(size_t)n * K_PRE + r];
    rx1[lane] = r4.x; ry1[lane] = r4.y; rx2[lane] = r4.z; ry2[lane] = r4.w;
    rar[lane] = (r4.z - r4.x) * (r4.w - r4.y);
    __syncthreads();

    u64 bits = 0;
    int bmax = 0;
    if (cok) { bmax = c - rb * 64; if (bmax > 64) bmax = 64; }
    for (int b = 0; b < bmax; ++b) {
        float ix = fminf(c4.z, rx2[b]) - fmaxf(c4.x, rx1[b]); ix = fmaxf(ix, 0.f);
        float iy = fminf(c4.w, ry2[b]) - fmaxf(c4.y, ry1[b]); iy = fmaxf(iy, 0.f);
        float inter = ix * iy;
        float iou = inter / (rar[b] + areaC - inter);
        if (iou > NMS_TH) bits |= (1ull << b);
    }
    maskT[((size_t)n * 32 + rb) * 2048 + c] = bits;
}

// ---------- greedy NMS: ballot-fixpoint per 64-block + output (tail zeroed) -
__global__ __launch_bounds__(64)
void k_scanT(const u64* __restrict__ maskT, const float* __restrict__ boxes_s,
             const float* __restrict__ scores_s, float* __restrict__ out) {
    int n = blockIdx.x;
    int lane = threadIdx.x;       // 64 threads, single wave
    __shared__ float ls[2048];
    __shared__ u64 keptw[32];
    for (int i = lane; i < 512; i += 64)
        ((float4*)ls)[i] = ((const float4*)(scores_s + (size_t)n * K_PRE))[i];
    // entries 2000..2047 come from the next image's scores (or garbage) — but
    // compact/sort guarantee slots >= cnt are zero-keyed and decode writes
    // exactly 2000; indices >= K_PRE are masked below via c < K_PRE semantics:
    if (lane < 48) ls[2000 + lane] = -1.0f;
    if (lane < 32) keptw[lane] = 0ull;
    __syncthreads();

    const u64* mb = maskT + (size_t)n * 32 * 2048;
    int kept_total = 0;

    u64 wv[32];
#pragma unroll
    for (int rb = 0; rb < 32; ++rb) wv[rb] = mb[(size_t)rb * 2048 + lane];

    for (int f = 0; f < 32; ++f) {
        int c = f * 64 + lane;

        u64 wn[32];
        if (f < 31) {
            int cn = c + 64;
#pragma unroll
            for (int rb = 0; rb < 32; ++rb) wn[rb] = mb[(size_t)rb * 2048 + cn];
        }

        // rb > f words may be unwritten garbage, but keptw[rb>=f] == 0
        u64 hit = 0;
#pragma unroll
        for (int rb = 0; rb < 32; ++rb) hit |= (wv[rb] & keptw[rb]);
        bool ext = hit != 0ull;
        u64 diag = wv[f];

        bool v = (ls[c] >= 0.0f) && !ext;
        u64 kept = __ballot(v);
        while (true) {
            u64 nk = __ballot(v && ((diag & kept) == 0ull));
            if (nk == kept) break;
            kept = nk;
        }

        if ((kept >> lane) & 1ull) {
            int rank = kept_total + (int)__popcll(kept & ((1ull << lane) - 1ull));
            if (rank < K_POST) {
                float4 b4 = ((const float4*)boxes_s)[(size_t)n * K_PRE + c];
                ((float4*)out)[(size_t)n * K_POST + rank] = b4;
                out[(size_t)NB * K_POST * 4 + (size_t)n * K_POST + rank] = ls[c];
            }
        }
        kept_total += (int)__popcll(kept);
        if (lane == 0) keptw[f] = kept;
        if (kept_total >= K_POST || f == 31) break;
#pragma unroll
        for (int rb = 0; rb < 32; ++rb) wv[rb] = wn[rb];
    }

    // zero output tail (every output byte written each replay)
    int start = (kept_total < K_POST) ? kept_total : K_POST;
    float4 z4; z4.x = z4.y = z4.z = z4.w = 0.f;
    for (int rk = start + lane; rk < K_POST; rk += 64) {
        ((float4*)out)[(size_t)n * K_POST + rk] = z4;
        out[(size_t)NB * K_POST * 4 + (size_t)n * K_POST + rk] = 0.f;
    }
}

extern "C" void kernel_launch(void* const* d_in, const int* in_sizes, int n_in,
                              void* d_out, int out_size, void* d_ws, size_t ws_size,
                              hipStream_t stream) {
    const float* cls     = (const float*)d_in[0];
    const float* regr    = (const float*)d_in[1];
    const float* anchors = (const float*)d_in[2];
    const int*   pih     = (const int*)d_in[3];
    const int*   piw     = (const int*)d_in[4];
    float* out = (float*)d_out;

    char* w = (char*)d_ws;
    u64*      maskT   = (u64*)(w + 0);                 // 8*32*2048*8 = 4,194,304
    unsigned* gh      = (unsigned*)(w + 4194304);      // 8*4096*4    =   131,072
    unsigned* selT12  = (unsigned*)(w + 4325376);      // 32
    u64*      cand    = (u64*)(w + 4325408);           // 8*4096*8    =   262,144
    float*    boxes_s = (float*)(w + 4587552);         // 8*2000*16   =   256,000
    float*    scores_s= (float*)(w + 4843552);         // 8*2000*4    =    64,000
    // end 4,907,552 bytes

    z_init<<<32, 256, 0, stream>>>((uint4*)gh, selT12);
    k_histF<<<dim3(HBLK, NB), 256, 0, stream>>>((const uint4*)cls, gh);
    k_sel<<<NB, 1024, 0, stream>>>(gh, selT12);
    k_histR<<<dim3(HBLK, NB), 256, 0, stream>>>((const uint4*)cls, gh, selT12);
    k_selR<<<NB, 1024, 0, stream>>>(gh, selT12);
    k_compact<<<dim3(CBLK, NB), 512, 0, stream>>>((const uint4*)cls, selT12, cand);
    k_sort<<<NB, 512, 0, stream>>>(cand);
    k_decode<<<NB, 1024, 0, stream>>>(regr, anchors, pih, piw,
                                      cand, boxes_s, scores_s);
    k_maskT<<<dim3(528, NB), 64, 0, stream>>>(boxes_s, maskT);
    k_scanT<<<NB, 64, 0, stream>>>(maskT, boxes_s, scores_s, out);
    (void)in_sizes; (void)n_in; (void)ws_size;
}

// Round 12
// 126.411 us; speedup vs baseline: 1.4029x; 1.0076x over previous
//
#include <hip/hip_runtime.h>
#include <hip/hip_bf16.h>
#include <stdint.h>

typedef unsigned long long u64;

#define AN 15
#define HH 200
#define WW 320
#define HWSZ (HH*WW)          // 64000
#define PER (AN*HWSZ)         // 960000 anchors per image
#define NB 8
#define K_PRE 2000
#define K_POST 1000
#define SORTN 4096            // candidate slot array per image
#define HBINS 4096
#define HBLK 64               // fused hist/compact blocks per image
#define FSLICE 512            // floor-buffer slots per block (mean 344, +9 sigma)
#define CBLK 16               // filter blocks per image
#define SLICE (SORTN/CBLK)    // 256 candidate slots per filter block
#define NMS_TH 0.7f
#define BBOX_CLIP_F 4.135166556742356f   // log(1000/16)
#define FLOOR12 3072u         // key12 of value 2.0f; P(x>=2.0)~2.3% for N(0,1)
#define SENT 0xFFFFFFFFu

// padded LDS index for the sort: lane stride 72B -> <=4-way bank conflicts
#define PHI(x) ((x) + ((x) >> 3))

__device__ __forceinline__ unsigned keyOfU(unsigned u) {
    return (u & 0x80000000u) ? ~u : (u | 0x80000000u);
}
__device__ __forceinline__ float valOf(unsigned k) {
    unsigned u = (k & 0x80000000u) ? (k ^ 0x80000000u) : ~k;
    return __uint_as_float(u);
}

// ---------- zero-init gh (131 KB) + selT12 sentinels ------------------------
__global__ __launch_bounds__(256)
void z_init(uint4* __restrict__ gh4, unsigned* __restrict__ selT12) {
    gh4[blockIdx.x * 256 + threadIdx.x] = make_uint4(0, 0, 0, 0);
    if (blockIdx.x == 0 && threadIdx.x < NB) selT12[threadIdx.x] = SENT;
}

// ---------- fused: floored hist + floor-buffer compaction (ONE 30.7MB pass) -
__global__ __launch_bounds__(256)
void k_hc(const uint4* __restrict__ cls4, unsigned* __restrict__ gh,
          u64* __restrict__ fbuf) {
    int n = blockIdx.y;
    __shared__ unsigned lh[HBINS];             // 16 KB
    __shared__ unsigned cnt;
    for (int b = threadIdx.x; b < HBINS; b += 256) lh[b] = 0;
    if (threadIdx.x == 0) cnt = 0;
    __syncthreads();
    u64* slice = fbuf + ((size_t)n * HBLK + blockIdx.x) * FSLICE;
    const uint4* p = cls4 + (size_t)n * (PER / 4);
    int stride = gridDim.x * 256;

#define PROC(vv, ii) {                                                        \
        unsigned kk[4] = {keyOfU((vv).x), keyOfU((vv).y), keyOfU((vv).z),     \
                          keyOfU((vv).w)};                                    \
        int i0 = (ii) * 4;                                                    \
        int a = i0 / HWSZ;                                                    \
        int r0 = i0 - a * HWSZ;                                               \
        _Pragma("unroll")                                                     \
        for (int c = 0; c < 4; ++c) {                                         \
            unsigned k12 = kk[c] >> 20;                                       \
            if (k12 >= FLOOR12) {                                             \
                atomicAdd(&lh[k12], 1u);                                      \
                unsigned pos = atomicAdd(&cnt, 1u);                           \
                if (pos < FSLICE) {                                           \
                    unsigned idx = (unsigned)((r0 + c) * AN + a);             \
                    slice[pos] = ((u64)kk[c] << 32) | (u64)(~idx);            \
                }                                                             \
            }                                                                 \
        }                                                                     \
    }

    int i = blockIdx.x * 256 + threadIdx.x;
    for (; i + stride < PER / 4; i += 2 * stride) {
        uint4 a4 = p[i];
        uint4 b4 = p[i + stride];
        PROC(a4, i) PROC(b4, i + stride)
    }
    if (i < PER / 4) { uint4 a4 = p[i]; PROC(a4, i) }
#undef PROC

    __syncthreads();
    unsigned c0 = cnt; if (c0 > FSLICE) c0 = FSLICE;
    for (unsigned t = c0 + threadIdx.x; t < FSLICE; t += 256) slice[t] = 0ull;
    unsigned* dst = gh + (size_t)n * HBINS;
    for (int b = threadIdx.x; b < HBINS; b += 256) {
        unsigned v = lh[b];
        if (v) atomicAdd(&dst[b], v);      // few nonzero bins
    }
}

// ---------- suffix-scan -> 12-bit threshold (writes only if crossing found) -
__global__ __launch_bounds__(1024)
void k_sel(const unsigned* __restrict__ gh, unsigned* __restrict__ selT12) {
    int n = blockIdx.x, t = threadIdx.x;
    __shared__ unsigned L[1024];
    uint4 v = *(const uint4*)(gh + (size_t)n * HBINS + 4 * t);
    unsigned sf[5];
    sf[3] = v.w; sf[2] = v.z + sf[3]; sf[1] = v.y + sf[2]; sf[0] = v.x + sf[1];
    L[t] = sf[0];
    __syncthreads();
    for (int off = 1; off < 1024; off <<= 1) {
        unsigned x = L[t] + ((t + off < 1024) ? L[t + off] : 0u);
        __syncthreads(); L[t] = x; __syncthreads();
    }
    unsigned tail = (t < 1023) ? L[t + 1] : 0u;
    sf[0] += tail; sf[1] += tail; sf[2] += tail; sf[3] += tail; sf[4] = tail;
#pragma unroll
    for (int e = 0; e < 4; ++e)
        if (sf[e] >= K_PRE && sf[e + 1] < K_PRE) selT12[n] = 4u * t + e;
}

// ---------- fallback: complete hist for keys < floor (early-exit if done) ---
__global__ __launch_bounds__(256)
void k_histR(const uint4* __restrict__ cls4, unsigned* __restrict__ gh,
             const unsigned* __restrict__ selT12) {
    int n = blockIdx.y;
    if (selT12[n] != SENT) return;             // normal case: ~free
    __shared__ unsigned lh[HBINS];
    for (int b = threadIdx.x; b < HBINS; b += 256) lh[b] = 0;
    __syncthreads();
    const uint4* p = cls4 + (size_t)n * (PER / 4);
    int stride = gridDim.x * 256;
#define H4(vv) { unsigned k0 = keyOfU((vv).x) >> 20, k1 = keyOfU((vv).y) >> 20, \
                          k2 = keyOfU((vv).z) >> 20, k3 = keyOfU((vv).w) >> 20; \
        if (k0 < FLOOR12) atomicAdd(&lh[k0], 1u);                               \
        if (k1 < FLOOR12) atomicAdd(&lh[k1], 1u);                               \
        if (k2 < FLOOR12) atomicAdd(&lh[k2], 1u);                               \
        if (k3 < FLOOR12) atomicAdd(&lh[k3], 1u); }
    for (int i = blockIdx.x * 256 + threadIdx.x; i < PER / 4; i += stride) {
        uint4 a = p[i]; H4(a)
    }
#undef H4
    __syncthreads();
    unsigned* dst = gh + (size_t)n * HBINS;
    for (int b = threadIdx.x; b < HBINS; b += 256) {
        unsigned v = lh[b];
        if (v) atomicAdd(&dst[b], v);
    }
}

__global__ __launch_bounds__(1024)
void k_selR(const unsigned* __restrict__ gh, unsigned* __restrict__ selT12) {
    int n = blockIdx.x, t = threadIdx.x;
    if (selT12[n] != SENT) return;
    __shared__ unsigned L[1024];
    uint4 v = *(const uint4*)(gh + (size_t)n * HBINS + 4 * t);
    unsigned sf[5];
    sf[3] = v.w; sf[2] = v.z + sf[3]; sf[1] = v.y + sf[2]; sf[0] = v.x + sf[1];
    L[t] = sf[0];
    __syncthreads();
    for (int off = 1; off < 1024; off <<= 1) {
        unsigned x = L[t] + ((t + off < 1024) ? L[t + off] : 0u);
        __syncthreads(); L[t] = x; __syncthreads();
    }
    unsigned tail = (t < 1023) ? L[t + 1] : 0u;
    sf[0] += tail; sf[1] += tail; sf[2] += tail; sf[3] += tail; sf[4] = tail;
#pragma unroll
    for (int e = 0; e < 4; ++e)
        if (sf[e] >= K_PRE && sf[e + 1] < K_PRE) selT12[n] = 4u * t + e;
}

// ---------- filter floor-buffer -> cand slices (2MB read, not 30.7MB) -------
__global__ __launch_bounds__(256)
void k_filter(const uint4* __restrict__ cls4, const u64* __restrict__ fbuf,
              const unsigned* __restrict__ selT12, u64* __restrict__ cand) {
    int n = blockIdx.y, cb = blockIdx.x;
    unsigned t12 = selT12[n];
    __shared__ unsigned cnt;
    if (threadIdx.x == 0) cnt = 0;
    __syncthreads();
    u64* slice = cand + (size_t)n * SORTN + (size_t)cb * SLICE;

    if (t12 >= FLOOR12) {
        // normal path: floor-buffer contains every key >= T12; zero slots fail
        const u64* src = fbuf + ((size_t)n * HBLK + (size_t)cb * (HBLK / CBLK)) * FSLICE;
        for (int t = threadIdx.x; t < (HBLK / CBLK) * FSLICE; t += 256) {
            u64 e = src[t];
            if ((unsigned)(e >> 52) >= t12) {
                unsigned pos = atomicAdd(&cnt, 1u);
                if (pos < SLICE) slice[pos] = e;
            }
        }
    } else {
        // degenerate fallback: rescan this block's interleaved 1/16 of cls
        const uint4* p = cls4 + (size_t)n * (PER / 4);
        int stride = gridDim.x * 256;
        for (int i = cb * 256 + threadIdx.x; i < PER / 4; i += stride) {
            uint4 v = p[i];
            unsigned kk[4] = {keyOfU(v.x), keyOfU(v.y), keyOfU(v.z), keyOfU(v.w)};
            int i0 = i * 4;
            int a = i0 / HWSZ;
            int r0 = i0 - a * HWSZ;
#pragma unroll
            for (int c = 0; c < 4; ++c) {
                if ((kk[c] >> 20) >= t12) {
                    unsigned pos = atomicAdd(&cnt, 1u);
                    if (pos < SLICE) {
                        unsigned idx = (unsigned)((r0 + c) * AN + a);
                        slice[pos] = ((u64)kk[c] << 32) | (u64)(~idx);
                    }
                }
            }
        }
    }
    __syncthreads();
    unsigned c0 = cnt; if (c0 > SLICE) c0 = SLICE;
    for (unsigned t = c0 + threadIdx.x; t < SLICE; t += 256) slice[t] = 0ull;
}

// ---------- register-hybrid bitonic sort of 4096 (PHI-padded LDS) -----------
__global__ __launch_bounds__(512)
void k_sort(u64* __restrict__ cand) {
    int n = blockIdx.x;
    int tid = threadIdx.x;
    __shared__ u64 sb[PHI(SORTN - 1) + 1];   // 4607 u64 = 36.9 KB
    u64 r[8];

#define CE(a_, b_, d_) { bool sw_ = (d_) ? (r[a_] < r[b_]) : (r[a_] > r[b_]); \
                         if (sw_) { u64 t_ = r[a_]; r[a_] = r[b_]; r[b_] = t_; } }

    {   // load own 8 elements, run k=2 and k=4 levels fully in registers
        const u64* src = cand + (size_t)n * SORTN + 8 * tid;
#pragma unroll
        for (int e = 0; e < 8; ++e) r[e] = src[e];
        CE(0, 1, true)  CE(2, 3, false) CE(4, 5, true)  CE(6, 7, false)
        CE(0, 2, true)  CE(1, 3, true)  CE(4, 6, false) CE(5, 7, false)
        CE(0, 1, true)  CE(2, 3, true)  CE(4, 5, false) CE(6, 7, false)
#pragma unroll
        for (int e = 0; e < 8; ++e) sb[9 * tid + e] = r[e];   // PHI(8t+e)
        __syncthreads();
    }

    for (int k = 8; k <= SORTN; k <<= 1) {
        for (int j = k >> 1; j >= 8; j >>= 1) {
#pragma unroll
            for (int s = 0; s < 4; ++s) {
                int c = tid + s * 512;
                int i = ((c & ~(j - 1)) << 1) | (c & (j - 1));
                int p = i | j;
                bool dir = (i & k) == 0;
                u64 a = sb[PHI(i)], b = sb[PHI(p)];
                bool sw = dir ? (a < b) : (a > b);
                if (sw) { sb[PHI(i)] = b; sb[PHI(p)] = a; }
            }
            __syncthreads();
        }
        {   // register pass: j = 4, 2, 1 (dir uniform per thread for k>=8)
            bool d = ((8 * tid) & k) == 0;
#pragma unroll
            for (int e = 0; e < 8; ++e) r[e] = sb[9 * tid + e];
            CE(0, 4, d) CE(1, 5, d) CE(2, 6, d) CE(3, 7, d)
            CE(0, 2, d) CE(1, 3, d) CE(4, 6, d) CE(5, 7, d)
            CE(0, 1, d) CE(2, 3, d) CE(4, 5, d) CE(6, 7, d)
#pragma unroll
            for (int e = 0; e < 8; ++e) sb[9 * tid + e] = r[e];
            __syncthreads();
        }
    }
#undef CE

    // write back only the top-2048 (decode reads top-2000)
    for (int t = tid; t < 2048; t += 512)
        cand[(size_t)n * SORTN + t] = sb[PHI(t)];
}

// ---------- decode top-2000 + stable valid-first partition (wide gathers) ---
__global__ __launch_bounds__(1024)
void k_decode(const float* __restrict__ reg, const float* __restrict__ anchors,
              const int* __restrict__ pih, const int* __restrict__ piw,
              const u64* __restrict__ cand,
              float* __restrict__ boxes_s, float* __restrict__ scores_s) {
    int n = blockIdx.x;
    int tid = threadIdx.x;
    float fh = (float)(*pih);
    float fw = (float)(*piw);

    float bx[2][4]; float sc[2]; int pred[2];
#pragma unroll
    for (int q = 0; q < 2; ++q) {
        int t = tid + 1024 * q;
        pred[q] = 0; sc[q] = -1.0f;
        bx[q][0] = bx[q][1] = bx[q][2] = bx[q][3] = 0.f;
        if (t < K_PRE) {
            u64 e = cand[(size_t)n * SORTN + t];
            unsigned key = (unsigned)(e >> 32);
            unsigned idx = ~((unsigned)e);
            float v = valOf(key);
            float s = 1.0f / (1.0f + expf(-v));
            int a = (int)(idx % AN);
            int rr = (int)(idx / AN);
            size_t base = ((size_t)(n * AN + a) * 4) * HWSZ + rr;
            float dx = reg[base];
            float dy = reg[base + HWSZ];
            float dw = reg[base + 2 * (size_t)HWSZ];
            float dh = reg[base + 3 * (size_t)HWSZ];
            float4 an4 = ((const float4*)anchors)[idx];
            float wa = an4.z - an4.x, ha = an4.w - an4.y;
            float cxa = an4.x + 0.5f * wa, cya = an4.y + 0.5f * ha;
            dw = fminf(dw, BBOX_CLIP_F); dh = fminf(dh, BBOX_CLIP_F);
            float cx = dx * wa + cxa, cy = dy * ha + cya;
            float w = wa * expf(dw), h = ha * expf(dh);
            float x1 = cx - 0.5f * w, y1 = cy - 0.5f * h;
            float x2 = cx + 0.5f * w, y2 = cy + 0.5f * h;
            x1 = fminf(fmaxf(x1, 0.f), fw);
            y1 = fminf(fmaxf(y1, 0.f), fh);
            x2 = fminf(fmaxf(x2, 0.f), fw);
            y2 = fminf(fmaxf(y2, 0.f), fh);
            bool valid = ((x2 - x1) >= 1.0f) && ((y2 - y1) >= 1.0f);
            bx[q][0] = x1; bx[q][1] = y1; bx[q][2] = x2; bx[q][3] = y2;
            sc[q] = s; pred[q] = valid ? 1 : 0;
        }
    }

    // stable valid-first partition via per-wave ballots (2048 entries)
    __shared__ u64 ww[32];
    __shared__ int wpfx[33];
    int lane = tid & 63, wid = tid >> 6;     // 16 waves
#pragma unroll
    for (int q = 0; q < 2; ++q) {
        u64 bal = __ballot(pred[q] != 0);
        if (lane == 0) ww[wid + 16 * q] = bal;
    }
    __syncthreads();
    if (tid == 0) {
        int s = 0;
#pragma unroll
        for (int w2 = 0; w2 < 32; ++w2) { wpfx[w2] = s; s += (int)__popcll(ww[w2]); }
        wpfx[32] = s;
    }
    __syncthreads();
    int V = wpfx[32];

#pragma unroll
    for (int q = 0; q < 2; ++q) {
        int t = tid + 1024 * q;
        if (t < K_PRE) {
            int wi = t >> 6;
            int before = wpfx[wi] + (int)__popcll(ww[wi] & ((1ull << (unsigned)lane) - 1ull));
            int pos = pred[q] ? before : (V + (t - before));
            float4 b4; b4.x = bx[q][0]; b4.y = bx[q][1]; b4.z = bx[q][2]; b4.w = bx[q][3];
            ((float4*)boxes_s)[(size_t)n * K_PRE + pos] = b4;
            scores_s[(size_t)n * K_PRE + pos] = pred[q] ? sc[q] : -1.0f;
        }
    }
}

// ---------- transposed IoU mask, triangular (rb,cb) tile per 64-thr block ---
__global__ __launch_bounds__(64)
void k_maskT(const float* __restrict__ boxes_s, u64* __restrict__ maskT) {
    int n = blockIdx.y;
    int p = blockIdx.x;                      // 0..527 triangular pair index
    int lane = threadIdx.x;
    int cb = (int)((sqrtf(8.0f * (float)p + 1.0f) - 1.0f) * 0.5f);
    while ((cb + 1) * (cb + 2) / 2 <= p) ++cb;
    while (cb * (cb + 1) / 2 > p) --cb;
    int rb = p - cb * (cb + 1) / 2;          // 0 <= rb <= cb < 32

    __shared__ float rx1[64], ry1[64], rx2[64], ry2[64], rar[64];
    int c = cb * 64 + lane;
    bool cok = c < K_PRE;
    float4 c4; c4.x = c4.y = c4.z = c4.w = 0.f;
    if (cok) c4 = ((const float4*)boxes_s)[(size_t)n * K_PRE + c];
    float areaC = (c4.z - c4.x) * (c4.w - c4.y);

    int r = rb * 64 + lane;
    float4 r4; r4.x = r4.y = r4.z = r4.w = 0.f;
    if (r < K_PRE) r4 = ((const float4*)boxes_s)[(size_t)n * K_PRE + r];
    rx1[lane] = r4.x; ry1[lane] = r4.y; rx2[lane] = r4.z; ry2[lane] = r4.w;
    rar[lane] = (r4.z - r4.x) * (r4.w - r4.y);
    __syncthreads();

    u64 bits = 0;
    int bmax = 0;
    if (cok) { bmax = c - rb * 64; if (bmax > 64) bmax = 64; }
    for (int b = 0; b < bmax; ++b) {
        float ix = fminf(c4.z, rx2[b]) - fmaxf(c4.x, rx1[b]); ix = fmaxf(ix, 0.f);
        float iy = fminf(c4.w, ry2[b]) - fmaxf(c4.y, ry1[b]); iy = fmaxf(iy, 0.f);
        float inter = ix * iy;
        float iou = inter / (rar[b] + areaC - inter);
        if (iou > NMS_TH) bits |= (1ull << b);
    }
    maskT[((size_t)n * 32 + rb) * 2048 + c] = bits;
}

// ---------- greedy NMS: ballot-fixpoint per 64-block + output (tail zeroed) -
__global__ __launch_bounds__(64)
void k_scanT(const u64* __restrict__ maskT, const float* __restrict__ boxes_s,
             const float* __restrict__ scores_s, float* __restrict__ out) {
    int n = blockIdx.x;
    int lane = threadIdx.x;       // 64 threads, single wave
    __shared__ float ls[2048];
    __shared__ u64 keptw[32];
    for (int i = lane; i < 500; i += 64)
        ((float4*)ls)[i] = ((const float4*)(scores_s + (size_t)n * K_PRE))[i];
    if (lane < 48) ls[2000 + lane] = -1.0f;
    if (lane < 32) keptw[lane] = 0ull;
    __syncthreads();

    const u64* mb = maskT + (size_t)n * 32 * 2048;
    int kept_total = 0;

    u64 wv[32];
#pragma unroll
    for (int rb = 0; rb < 32; ++rb) wv[rb] = mb[(size_t)rb * 2048 + lane];

    for (int f = 0; f < 32; ++f) {
        int c = f * 64 + lane;

        u64 wn[32];
        if (f < 31) {
            int cn = c + 64;
#pragma unroll
            for (int rb = 0; rb < 32; ++rb) wn[rb] = mb[(size_t)rb * 2048 + cn];
        }

        // rb > f words may be unwritten garbage, but keptw[rb>=f] == 0
        u64 hit = 0;
#pragma unroll
        for (int rb = 0; rb < 32; ++rb) hit |= (wv[rb] & keptw[rb]);
        bool ext = hit != 0ull;
        u64 diag = wv[f];

        bool v = (ls[c] >= 0.0f) && !ext;
        u64 kept = __ballot(v);
        while (true) {
            u64 nk = __ballot(v && ((diag & kept) == 0ull));
            if (nk == kept) break;
            kept = nk;
        }

        if ((kept >> lane) & 1ull) {
            int rank = kept_total + (int)__popcll(kept & ((1ull << lane) - 1ull));
            if (rank < K_POST) {
                float4 b4 = ((const float4*)boxes_s)[(size_t)n * K_PRE + c];
                ((float4*)out)[(size_t)n * K_POST + rank] = b4;
                out[(size_t)NB * K_POST * 4 + (size_t)n * K_POST + rank] = ls[c];
            }
        }
        kept_total += (int)__popcll(kept);
        if (lane == 0) keptw[f] = kept;
        if (kept_total >= K_POST || f == 31) break;
#pragma unroll
        for (int rb = 0; rb < 32; ++rb) wv[rb] = wn[rb];
    }

    // zero output tail (every output byte written each replay)
    int start = (kept_total < K_POST) ? kept_total : K_POST;
    float4 z4; z4.x = z4.y = z4.z = z4.w = 0.f;
    for (int rk = start + lane; rk < K_POST; rk += 64) {
        ((float4*)out)[(size_t)n * K_POST + rk] = z4;
        out[(size_t)NB * K_POST * 4 + (size_t)n * K_POST + rk] = 0.f;
    }
}

extern "C" void kernel_launch(void* const* d_in, const int* in_sizes, int n_in,
                              void* d_out, int out_size, void* d_ws, size_t ws_size,
                              hipStream_t stream) {
    const float* cls     = (const float*)d_in[0];
    const float* regr    = (const float*)d_in[1];
    const float* anchors = (const float*)d_in[2];
    const int*   pih     = (const int*)d_in[3];
    const int*   piw     = (const int*)d_in[4];
    float* out = (float*)d_out;

    char* w = (char*)d_ws;
    u64*      maskT   = (u64*)(w + 0);                 // 8*32*2048*8 = 4,194,304
    unsigned* gh      = (unsigned*)(w + 4194304);      // 8*4096*4    =   131,072
    unsigned* selT12  = (unsigned*)(w + 4325376);      // 32 (pad to 64)
    u64*      cand    = (u64*)(w + 4325440);           // 8*4096*8    =   262,144
    float*    boxes_s = (float*)(w + 4587584);         // 8*2000*16   =   256,000
    float*    scores_s= (float*)(w + 4843584);         // 8*2000*4    =    64,000
    u64*      fbuf    = (u64*)(w + 4907584);           // 8*64*512*8  = 2,097,152
    // end 7,004,736 bytes

    z_init<<<32, 256, 0, stream>>>((uint4*)gh, selT12);
    k_hc<<<dim3(HBLK, NB), 256, 0, stream>>>((const uint4*)cls, gh, fbuf);
    k_sel<<<NB, 1024, 0, stream>>>(gh, selT12);
    k_histR<<<dim3(HBLK, NB), 256, 0, stream>>>((const uint4*)cls, gh, selT12);
    k_selR<<<NB, 1024, 0, stream>>>(gh, selT12);
    k_filter<<<dim3(CBLK, NB), 256, 0, stream>>>((const uint4*)cls, fbuf, selT12, cand);
    k_sort<<<NB, 512, 0, stream>>>(cand);
    k_decode<<<NB, 1024, 0, stream>>>(regr, anchors, pih, piw,
                                      cand, boxes_s, scores_s);
    k_maskT<<<dim3(528, NB), 64, 0, stream>>>(boxes_s, maskT);
    k_scanT<<<NB, 64, 0, stream>>>(maskT, boxes_s, scores_s, out);
    (void)in_sizes; (void)n_in; (void)ws_size;
}